// Round 11
// baseline (212.109 us; speedup 1.0000x reference)
//
#include <hip/hip_runtime.h>

// CasualSelfAttention fused block for MI355X (gfx950).
// B=4, T=2048, C=1024, H=16, D=64.
// x->bf16 conv -> weight transpose+conv -> 2-phase dbuf 128x128 QKV GEMM (Q pre-scaled,
// V written transposed) -> flash attention v5 (2 waves x 64q, K+V DMA dbuf, 1024-block
// LPT-balanced grid = 8 waves/CU) -> proj GEMM.
// Workspace (75,497,472 B):
//   [0,        33554432)  qk  bf16 [B,T,2C]      (Q cols 0..1023 pre-scaled, K cols 1024..2047)
//   [33554432, 50331648)  vT  bf16 [B*H][64][T]
//   [50331648, 67108864)  xbf bf16 [B,T,C]  (QKV phase)  /  attn bf16 [B,T,C] (flash+proj phase)
//   [67108864, 73400320)  w_attn^T bf16 [3C][C]
//   [73400320, 75497472)  w_proj^T bf16 [C][C]

using u16 = unsigned short;
using u32 = unsigned int;
using bf16x8 = __attribute__((ext_vector_type(8))) __bf16;
using f32x4  = __attribute__((ext_vector_type(4))) float;
using f32x16 = __attribute__((ext_vector_type(16))) float;
using u16x8  = __attribute__((ext_vector_type(8))) u16;
using u16x4  = __attribute__((ext_vector_type(4))) u16;
using u32x2  = __attribute__((ext_vector_type(2))) u32;
using u32x4  = __attribute__((ext_vector_type(4))) u32;
using fvec4  = __attribute__((ext_vector_type(4))) float;

__device__ __forceinline__ u16 f2bf(float f) {
  u32 u = __builtin_bit_cast(u32, f);
  u32 r = (u + 0x7FFFu + ((u >> 16) & 1u)) >> 16;
  return (u16)r;
}

__device__ __forceinline__ u32 cvtpk(float lo, float hi) {
  u32 r;
  asm("v_cvt_pk_bf16_f32 %0, %1, %2" : "=v"(r) : "v"(lo), "v"(hi));
  return r;
}

__device__ __forceinline__ f32x4 mfma16(bf16x8 a, bf16x8 b, f32x4 c) {
  return __builtin_amdgcn_mfma_f32_16x16x32_bf16(a, b, c, 0, 0, 0);
}

__device__ __forceinline__ f32x16 mfma32(bf16x8 a, bf16x8 b, f32x16 c) {
  return __builtin_amdgcn_mfma_f32_32x32x16_bf16(a, b, c, 0, 0, 0);
}

__device__ __forceinline__ void gld16(const u16* g, u16* l) {
  __builtin_amdgcn_global_load_lds(
      (const __attribute__((address_space(1))) void*)g,
      (__attribute__((address_space(3))) void*)l, 16, 0, 0);
}

// ---------------- f32 -> bf16 bulk convert ----------------
__global__ __launch_bounds__(256) void conv_kernel(
    const float* __restrict__ in, u16* __restrict__ out) {
  const size_t i = ((size_t)blockIdx.x * 256 + threadIdx.x) * 8;
  fvec4 a = *(const fvec4*)(in + i);
  fvec4 b = *(const fvec4*)(in + i + 4);
  u16x8 h;
#pragma unroll
  for (int j = 0; j < 4; ++j) { h[j] = f2bf(a[j]); h[4 + j] = f2bf(b[j]); }
  *(u16x8*)(out + i) = h;
}

// ---------------- transpose + f32->bf16 convert: W[K][N] -> Wt[N][K] ----------------
__global__ __launch_bounds__(256) void transpose_conv_kernel(
    const float* __restrict__ W, u16* __restrict__ Wt, int K, int N) {
  __shared__ float tile[32][33];
  const int n0 = blockIdx.x * 32, k0 = blockIdx.y * 32;
  const int tx = threadIdx.x, ty = threadIdx.y;  // 32 x 8
#pragma unroll
  for (int j = 0; j < 4; ++j)
    tile[ty + j * 8][tx] = W[(size_t)(k0 + ty + j * 8) * N + n0 + tx];
  __syncthreads();
#pragma unroll
  for (int j = 0; j < 4; ++j)
    Wt[(size_t)(n0 + ty + j * 8) * K + k0 + tx] = f2bf(tile[tx][ty + j * 8]);
}

// ---------------- 128x128x32 2-phase dbuf bf16 GEMM (round-8 proven) ----------------
template <bool QKV>
__global__ __launch_bounds__(256) void gemm_kernel(
    const u16* __restrict__ A, const u16* __restrict__ Bt,
    const float* __restrict__ bias, void* __restrict__ Cp,
    u16* __restrict__ vt, int M, int N, int K) {
  constexpr float SC = 0.18033688011112042f;  // 0.125 * log2(e)
  __shared__ u16 As[2][4096];
  __shared__ u16 Bs[2][4096];
  const int tid = threadIdx.x;
  const int l = tid & 63, w = tid >> 6;
  const int l15 = l & 15, l16 = l >> 4;
  const int wm = (w >> 1) * 64, wn = (w & 1) * 64;

  const u32 nwg = gridDim.x * gridDim.y;
  u32 f = blockIdx.y * gridDim.x + blockIdx.x;
  f = (f & 7) * (nwg >> 3) + (f >> 3);
  const long mbase = (long)(f / gridDim.x) * 128;
  const long nbase = (long)(f % gridDim.x) * 128;

  const int srow = tid >> 2;
  const int scol = ((tid & 3) ^ ((srow >> 1) & 3)) * 8;
  const u16* gA0 = A + (mbase + srow) * (long)K + scol;
  const u16* gA1 = gA0 + 64 * (long)K;
  const u16* gB0 = Bt + (nbase + srow) * (long)K + scol;
  const u16* gB1 = gB0 + 64 * (long)K;

  f32x4 acc[4][4] = {};
  const int NT = K >> 5;

#define STAGE(buf, koff)                         \
  gld16(gA0 + (koff), &As[buf][tid * 8]);        \
  gld16(gA1 + (koff), &As[buf][tid * 8 + 2048]); \
  gld16(gB0 + (koff), &Bs[buf][tid * 8]);        \
  gld16(gB1 + (koff), &Bs[buf][tid * 8 + 2048]);

  STAGE(0, 0);
  asm volatile("s_waitcnt vmcnt(0)" ::: "memory");
  __builtin_amdgcn_s_barrier();

  for (int t = 0; t < NT; ++t) {
    const int cur = t & 1;
    if (t + 1 < NT) { STAGE(cur ^ 1, (t + 1) * 32); }

    bf16x8 af[4], bfr[4];
#pragma unroll
    for (int i = 0; i < 4; ++i) {
      const int row = wm + i * 16 + l15;
      af[i] = *(const bf16x8*)(&As[cur][row * 32 + ((l16 ^ ((row >> 1) & 3)) * 8)]);
    }
#pragma unroll
    for (int j = 0; j < 4; ++j) {
      const int row = wn + j * 16 + l15;
      bfr[j] = *(const bf16x8*)(&Bs[cur][row * 32 + ((l16 ^ ((row >> 1) & 3)) * 8)]);
    }
    asm volatile("s_waitcnt lgkmcnt(0)" ::: "memory");
    __builtin_amdgcn_sched_barrier(0);
    __builtin_amdgcn_s_setprio(1);
#pragma unroll
    for (int i = 0; i < 4; ++i)
#pragma unroll
      for (int j = 0; j < 4; ++j)
        acc[i][j] = mfma16(af[i], bfr[j], acc[i][j]);
    __builtin_amdgcn_s_setprio(0);
    __builtin_amdgcn_sched_barrier(0);
    if (t + 1 < NT) { asm volatile("s_waitcnt vmcnt(0)" ::: "memory"); }
    __builtin_amdgcn_s_barrier();
  }
#undef STAGE

  if constexpr (QKV) {
    const bool isv = (nbase >= 2048);
#pragma unroll
    for (int i = 0; i < 4; ++i) {
#pragma unroll
      for (int j = 0; j < 4; ++j) {
        const long m0 = mbase + wm + i * 16 + l16 * 4;
        const int n = (int)nbase + wn + j * 16 + l15;
        const float bv = bias[n];
        if (!isv) {
          u16* qkp = (u16*)Cp;
          const float sc = (n < 1024) ? SC : 1.0f;
#pragma unroll
          for (int r = 0; r < 4; ++r)
            qkp[(m0 + r) * 2048 + n] = f2bf((acc[i][j][r] + bv) * sc);
        } else {
          const int vc = n - 2048, hh = vc >> 6, dd = vc & 63;
          const int bb = (int)(m0 >> 11), t0 = (int)(m0 & 2047);
          u16x4 pk;
#pragma unroll
          for (int r = 0; r < 4; ++r) pk[r] = f2bf(acc[i][j][r] + bv);
          *(u16x4*)(vt + ((size_t)(bb * 16 + hh) * 64 + dd) * 2048 + t0) = pk;
        }
      }
    }
  } else {
#pragma unroll
    for (int i = 0; i < 4; ++i) {
#pragma unroll
      for (int j = 0; j < 4; ++j) {
        const long row0 = mbase + wm + i * 16 + l16 * 4;
        const long col = nbase + wn + j * 16 + l15;
        const float bv = bias[col];
#pragma unroll
        for (int r = 0; r < 4; ++r)
          ((float*)Cp)[(row0 + r) * (long)N + col] = acc[i][j][r] + bv;
      }
    }
  }
}

// ---------------- flash attention v5: 2 waves x 64q, 1024-block LPT grid ----------------
// grid 1024 = 16 qt x 64 bh; block = 128 threads = 2 waves x 64 q (QBLK=128).
// Remap: i<512 -> qt=15-(i>>6) (heavy first); else qt=(i-512)>>6. CU c's resident set
// {c, c+256, c+512, c+768} sums to 34 work-units for every c -> perfectly balanced,
// 4 blocks/CU = 8 waves/CU (restores cross-wave MFMA||VALU overlap lost in v4).
// bh = i&63 -> all 16 blocks of one (b,h) on one XCD.
// Each LDS K/V fragment feeds 2 mfma32 (one per q-group) -> LDS reads/MFMA halved.
// K,V staged by global_load_lds DMA (pre-swizzled source); one barrier/iter.
// Softmax p = exp2(s) (shift cancels in normalization exactly).
__global__ __launch_bounds__(128) void flash_kernel(
    const u16* __restrict__ qk, const u16* __restrict__ vt, u16* __restrict__ attn_out) {
  __shared__ u16 Ks[2][64 * 64];  // [buf][key][64 d], slot^=(row&7) swizzle
  __shared__ u16 Vs[2][64 * 64];  // [buf][d][64 key]
  const int tid = threadIdx.x;
  const int lane = tid & 63, w = tid >> 6;  // w in 0..1
  const int l31 = lane & 31, hi = lane >> 5;
  const int xorv = (l31 & 7) << 4;

  const int i = blockIdx.x;
  const int bh = i & 63;
  const int qt = (i < 512) ? (15 - (i >> 6)) : ((i - 512) >> 6);
  const int b = bh >> 4, h = bh & 15;
  const u16* qbase = qk + (size_t)b * 2048 * 2048 + h * 64;
  const u16* kbase = qbase + 1024;
  const u16* vbase = vt + (size_t)bh * 64 * 2048;
  u16* obase = attn_out + (size_t)b * 2048 * 1024 + h * 64;

  // DMA staging: thread covers rows sr, sr+32 per tile; 16B slot pre-swizzled
  const int sr = tid >> 3;
  const int ss = (tid & 7) ^ (sr & 7);
  const u16* gk = kbase + (size_t)sr * 2048 + ss * 8;
  const u16* gv = vbase + (size_t)sr * 2048 + ss * 8;
  const int dofs = tid * 8;

  const int nt = 2 * qt + 2;
  const int qr0 = qt * 128 + w * 64;
  const int ktmax = 2 * qt + w;  // last useful tile for this wave

  // Q B-frags for both 32-q groups: col=q, k(d) = ds*16 + hi*8 + e
  bf16x8 qf[2][4];
#pragma unroll
  for (int g = 0; g < 2; ++g)
#pragma unroll
    for (int ds = 0; ds < 4; ++ds)
      qf[g][ds] = *(const bf16x8*)(qbase + (size_t)(qr0 + g * 32 + l31) * 2048 + ds * 16 + hi * 8);

  f32x16 oaccA[2] = {}, oaccB[2] = {};  // [dh] per q-group
  float lsumA = 0.f, lsumB = 0.f;

  // prologue: DMA K,V tile 0 into buf 0
#pragma unroll
  for (int j = 0; j < 4; ++j) {
    gld16(gk + (size_t)(j * 16) * 2048, &Ks[0][j * 1024 + dofs]);
    gld16(gv + (size_t)(j * 16) * 2048, &Vs[0][j * 1024 + dofs]);
  }
  asm volatile("s_waitcnt vmcnt(0)" ::: "memory");
  __builtin_amdgcn_s_barrier();

  int cur = 0;
  for (int kt = 0; kt < nt; ++kt) {
    const int kb = kt * 64;
    if (kt + 1 < nt) {  // DMA next tile into other buffer; lands under compute
#pragma unroll
      for (int j = 0; j < 4; ++j) {
        gld16(gk + (size_t)(kb + 64 + j * 16) * 2048, &Ks[cur ^ 1][j * 1024 + dofs]);
        gld16(gv + (size_t)(j * 16) * 2048 + (kb + 64), &Vs[cur ^ 1][j * 1024 + dofs]);
      }
    }

    if (kt <= ktmax) {  // skip fully-masked tiles (wave 0 on the block's last tile)
      bf16x8 pfA[4], pfB[4];
#pragma unroll
      for (int kh = 0; kh < 2; ++kh) {
        // S^T = K Q^T for this 32-key half; K-frag reused across both q-groups
        f32x16 sA = {}, sB = {};
        __builtin_amdgcn_s_setprio(1);
#pragma unroll
        for (int ds = 0; ds < 4; ++ds) {
          const int row = kh * 32 + l31;
          bf16x8 kf = *(const bf16x8*)((const char*)&Ks[cur][0] + row * 128 + ((ds * 32 + hi * 16) ^ xorv));
          sA = mfma32(kf, qf[0][ds], sA);
          sB = mfma32(kf, qf[1][ds], sB);
        }
        __builtin_amdgcn_s_setprio(0);

        if (kb + kh * 32 + 31 > qr0) {  // causal mask
#pragma unroll
          for (int r = 0; r < 16; ++r) {
            const int key = kb + kh * 32 + (r & 3) + 8 * (r >> 2) + 4 * hi;
            if (key > qr0 + l31) sA[r] = -1e30f;
            if (key > qr0 + 32 + l31) sB[r] = -1e30f;
          }
        }

        // p = exp2(s) in place; per-lane lsum
        float psA = 0.f, psB = 0.f;
#pragma unroll
        for (int r = 0; r < 16; ++r) {
          sA[r] = exp2f(sA[r]); psA += sA[r];
          sB[r] = exp2f(sB[r]); psB += sB[r];
        }
        lsumA += psA; lsumB += psB;

        // pack to PV B-frags: cvt_pk + permlane32_swap (in-register)
#pragma unroll
        for (int c = 0; c < 2; ++c) {
          const int bs = c * 8;
          {
            u32 L0 = cvtpk(sA[bs + 0], sA[bs + 1]);
            u32 L1 = cvtpk(sA[bs + 2], sA[bs + 3]);
            u32 L2 = cvtpk(sA[bs + 4], sA[bs + 5]);
            u32 L3 = cvtpk(sA[bs + 6], sA[bs + 7]);
            asm("v_permlane32_swap_b32 %0, %1" : "+v"(L0), "+v"(L2));
            asm("v_permlane32_swap_b32 %0, %1" : "+v"(L1), "+v"(L3));
            u32x4 pk = {L0, L1, L2, L3};
            pfA[kh * 2 + c] = __builtin_bit_cast(bf16x8, pk);
          }
          {
            u32 L0 = cvtpk(sB[bs + 0], sB[bs + 1]);
            u32 L1 = cvtpk(sB[bs + 2], sB[bs + 3]);
            u32 L2 = cvtpk(sB[bs + 4], sB[bs + 5]);
            u32 L3 = cvtpk(sB[bs + 6], sB[bs + 7]);
            asm("v_permlane32_swap_b32 %0, %1" : "+v"(L0), "+v"(L2));
            asm("v_permlane32_swap_b32 %0, %1" : "+v"(L1), "+v"(L3));
            u32x4 pk = {L0, L1, L2, L3};
            pfB[kh * 2 + c] = __builtin_bit_cast(bf16x8, pk);
          }
        }
      }

      // O^T += V^T P : V-frag reused across both q-groups
      __builtin_amdgcn_s_setprio(1);
#pragma unroll
      for (int dh = 0; dh < 2; ++dh) {
#pragma unroll
        for (int ks = 0; ks < 4; ++ks) {
          const int row = dh * 32 + l31;
          bf16x8 vf = *(const bf16x8*)((const char*)&Vs[cur][0] + row * 128 + ((ks * 32 + hi * 16) ^ xorv));
          if (dh == 0) {
            oaccA[0] = mfma32(vf, pfA[ks], oaccA[0]);
            oaccB[0] = mfma32(vf, pfB[ks], oaccB[0]);
          } else {
            oaccA[1] = mfma32(vf, pfA[ks], oaccA[1]);
            oaccB[1] = mfma32(vf, pfB[ks], oaccB[1]);
          }
        }
      }
      __builtin_amdgcn_s_setprio(0);
    }

    asm volatile("s_waitcnt vmcnt(0)" ::: "memory");  // next-tile DMAs resident
    __builtin_amdgcn_s_barrier();                     // all waves done with buf[cur]
    cur ^= 1;
  }

  // epilogue per q-group: row-sum with partner lane, lane-local normalize, packed store
#pragma unroll
  for (int g = 0; g < 2; ++g) {
    float ls = g ? lsumB : lsumA;
    ls += __shfl_xor(ls, 32);
    const float inv = 1.0f / ls;
    u16* orow = obase + (size_t)(qr0 + g * 32 + l31) * 1024;
#pragma unroll
    for (int dh = 0; dh < 2; ++dh) {
      const f32x16& oa = g ? oaccB[dh] : oaccA[dh];
#pragma unroll
      for (int jq = 0; jq < 4; ++jq) {
        u32x2 pk;
        pk[0] = cvtpk(oa[jq * 4 + 0] * inv, oa[jq * 4 + 1] * inv);
        pk[1] = cvtpk(oa[jq * 4 + 2] * inv, oa[jq * 4 + 3] * inv);
        *(u32x2*)(orow + dh * 32 + 8 * jq + 4 * hi) = pk;
      }
    }
  }
}

extern "C" void kernel_launch(void* const* d_in, const int* in_sizes, int n_in,
                              void* d_out, int out_size, void* d_ws, size_t ws_size,
                              hipStream_t stream) {
  (void)in_sizes; (void)n_in; (void)out_size; (void)ws_size;
  const float* x      = (const float*)d_in[0];  // [4,2048,1024]
  const float* w_attn = (const float*)d_in[1];  // [1024,3072]
  const float* b_attn = (const float*)d_in[2];  // [3072]
  const float* w_proj = (const float*)d_in[3];  // [1024,1024]
  const float* b_proj = (const float*)d_in[4];  // [1024]
  float* out = (float*)d_out;                   // [4,2048,1024] f32

  char* ws = (char*)d_ws;
  u16* qkbuf = (u16*)(ws);                   // 33,554,432 B
  u16* vtbuf = (u16*)(ws + 33554432);        // 16,777,216 B
  u16* xbf   = (u16*)(ws + 50331648);        // 16,777,216 B (reused as attn after QKV)
  u16* attnb = (u16*)(ws + 50331648);
  u16* wtA   = (u16*)(ws + 67108864);        //  6,291,456 B
  u16* wtP   = (u16*)(ws + 73400320);        //  2,097,152 B

  conv_kernel<<<4096, 256, 0, stream>>>(x, xbf);
  transpose_conv_kernel<<<dim3(3072 / 32, 1024 / 32), dim3(32, 8), 0, stream>>>(w_attn, wtA, 1024, 3072);
  transpose_conv_kernel<<<dim3(1024 / 32, 1024 / 32), dim3(32, 8), 0, stream>>>(w_proj, wtP, 1024, 1024);

  // QKV GEMM: xbf[8192,1024] @ w_attn^T -> qk (Q pre-scaled) + vT
  gemm_kernel<true><<<dim3(3072 / 128, 8192 / 128), 256, 0, stream>>>(
      xbf, wtA, b_attn, qkbuf, vtbuf, 8192, 3072, 1024);

  // flash attention (1024 LPT-balanced blocks)
  flash_kernel<<<1024, 128, 0, stream>>>(qkbuf, vtbuf, attnb);

  // output projection
  gemm_kernel<false><<<dim3(1024 / 128, 8192 / 128), 256, 0, stream>>>(
      attnb, wtP, b_proj, out, nullptr, 8192, 1024, 1024);
}

// Round 12
// 178.463 us; speedup vs baseline: 1.1885x; 1.1885x over previous
//
#include <hip/hip_runtime.h>

// CasualSelfAttention fused block for MI355X (gfx950).
// B=4, T=2048, C=1024, H=16, D=64.
// x->bf16 conv -> weight transpose+conv -> 2-phase dbuf 128x128 QKV GEMM (Q pre-scaled,
// V written transposed) -> flash v6 (r8 geometry: 4 waves x 32q, paired, 8 waves/CU;
// + DMA K/V staging + shift-free softmax + causal tile-skip) -> proj GEMM.
// Workspace (75,497,472 B):
//   [0,        33554432)  qk  bf16 [B,T,2C]      (Q cols 0..1023 pre-scaled, K cols 1024..2047)
//   [33554432, 50331648)  vT  bf16 [B*H][64][T]
//   [50331648, 67108864)  xbf bf16 [B,T,C]  (QKV phase)  /  attn bf16 [B,T,C] (flash+proj phase)
//   [67108864, 73400320)  w_attn^T bf16 [3C][C]
//   [73400320, 75497472)  w_proj^T bf16 [C][C]

using u16 = unsigned short;
using u32 = unsigned int;
using bf16x8 = __attribute__((ext_vector_type(8))) __bf16;
using f32x4  = __attribute__((ext_vector_type(4))) float;
using f32x16 = __attribute__((ext_vector_type(16))) float;
using u16x8  = __attribute__((ext_vector_type(8))) u16;
using u16x4  = __attribute__((ext_vector_type(4))) u16;
using u32x2  = __attribute__((ext_vector_type(2))) u32;
using u32x4  = __attribute__((ext_vector_type(4))) u32;
using fvec4  = __attribute__((ext_vector_type(4))) float;

__device__ __forceinline__ u16 f2bf(float f) {
  u32 u = __builtin_bit_cast(u32, f);
  u32 r = (u + 0x7FFFu + ((u >> 16) & 1u)) >> 16;
  return (u16)r;
}

__device__ __forceinline__ u32 cvtpk(float lo, float hi) {
  u32 r;
  asm("v_cvt_pk_bf16_f32 %0, %1, %2" : "=v"(r) : "v"(lo), "v"(hi));
  return r;
}

__device__ __forceinline__ f32x4 mfma16(bf16x8 a, bf16x8 b, f32x4 c) {
  return __builtin_amdgcn_mfma_f32_16x16x32_bf16(a, b, c, 0, 0, 0);
}

__device__ __forceinline__ f32x16 mfma32(bf16x8 a, bf16x8 b, f32x16 c) {
  return __builtin_amdgcn_mfma_f32_32x32x16_bf16(a, b, c, 0, 0, 0);
}

__device__ __forceinline__ void gld16(const u16* g, u16* l) {
  __builtin_amdgcn_global_load_lds(
      (const __attribute__((address_space(1))) void*)g,
      (__attribute__((address_space(3))) void*)l, 16, 0, 0);
}

// ---------------- f32 -> bf16 bulk convert ----------------
__global__ __launch_bounds__(256) void conv_kernel(
    const float* __restrict__ in, u16* __restrict__ out) {
  const size_t i = ((size_t)blockIdx.x * 256 + threadIdx.x) * 8;
  fvec4 a = *(const fvec4*)(in + i);
  fvec4 b = *(const fvec4*)(in + i + 4);
  u16x8 h;
#pragma unroll
  for (int j = 0; j < 4; ++j) { h[j] = f2bf(a[j]); h[4 + j] = f2bf(b[j]); }
  *(u16x8*)(out + i) = h;
}

// ---------------- transpose + f32->bf16 convert: W[K][N] -> Wt[N][K] ----------------
__global__ __launch_bounds__(256) void transpose_conv_kernel(
    const float* __restrict__ W, u16* __restrict__ Wt, int K, int N) {
  __shared__ float tile[32][33];
  const int n0 = blockIdx.x * 32, k0 = blockIdx.y * 32;
  const int tx = threadIdx.x, ty = threadIdx.y;  // 32 x 8
#pragma unroll
  for (int j = 0; j < 4; ++j)
    tile[ty + j * 8][tx] = W[(size_t)(k0 + ty + j * 8) * N + n0 + tx];
  __syncthreads();
#pragma unroll
  for (int j = 0; j < 4; ++j)
    Wt[(size_t)(n0 + ty + j * 8) * K + k0 + tx] = f2bf(tile[tx][ty + j * 8]);
}

// ---------------- 128x128x32 2-phase dbuf bf16 GEMM (round-8 proven) ----------------
template <bool QKV>
__global__ __launch_bounds__(256) void gemm_kernel(
    const u16* __restrict__ A, const u16* __restrict__ Bt,
    const float* __restrict__ bias, void* __restrict__ Cp,
    u16* __restrict__ vt, int M, int N, int K) {
  constexpr float SC = 0.18033688011112042f;  // 0.125 * log2(e)
  __shared__ u16 As[2][4096];
  __shared__ u16 Bs[2][4096];
  const int tid = threadIdx.x;
  const int l = tid & 63, w = tid >> 6;
  const int l15 = l & 15, l16 = l >> 4;
  const int wm = (w >> 1) * 64, wn = (w & 1) * 64;

  const u32 nwg = gridDim.x * gridDim.y;
  u32 f = blockIdx.y * gridDim.x + blockIdx.x;
  f = (f & 7) * (nwg >> 3) + (f >> 3);
  const long mbase = (long)(f / gridDim.x) * 128;
  const long nbase = (long)(f % gridDim.x) * 128;

  const int srow = tid >> 2;
  const int scol = ((tid & 3) ^ ((srow >> 1) & 3)) * 8;
  const u16* gA0 = A + (mbase + srow) * (long)K + scol;
  const u16* gA1 = gA0 + 64 * (long)K;
  const u16* gB0 = Bt + (nbase + srow) * (long)K + scol;
  const u16* gB1 = gB0 + 64 * (long)K;

  f32x4 acc[4][4] = {};
  const int NT = K >> 5;

#define STAGE(buf, koff)                         \
  gld16(gA0 + (koff), &As[buf][tid * 8]);        \
  gld16(gA1 + (koff), &As[buf][tid * 8 + 2048]); \
  gld16(gB0 + (koff), &Bs[buf][tid * 8]);        \
  gld16(gB1 + (koff), &Bs[buf][tid * 8 + 2048]);

  STAGE(0, 0);
  asm volatile("s_waitcnt vmcnt(0)" ::: "memory");
  __builtin_amdgcn_s_barrier();

  for (int t = 0; t < NT; ++t) {
    const int cur = t & 1;
    if (t + 1 < NT) { STAGE(cur ^ 1, (t + 1) * 32); }

    bf16x8 af[4], bfr[4];
#pragma unroll
    for (int i = 0; i < 4; ++i) {
      const int row = wm + i * 16 + l15;
      af[i] = *(const bf16x8*)(&As[cur][row * 32 + ((l16 ^ ((row >> 1) & 3)) * 8)]);
    }
#pragma unroll
    for (int j = 0; j < 4; ++j) {
      const int row = wn + j * 16 + l15;
      bfr[j] = *(const bf16x8*)(&Bs[cur][row * 32 + ((l16 ^ ((row >> 1) & 3)) * 8)]);
    }
    asm volatile("s_waitcnt lgkmcnt(0)" ::: "memory");
    __builtin_amdgcn_sched_barrier(0);
    __builtin_amdgcn_s_setprio(1);
#pragma unroll
    for (int i = 0; i < 4; ++i)
#pragma unroll
      for (int j = 0; j < 4; ++j)
        acc[i][j] = mfma16(af[i], bfr[j], acc[i][j]);
    __builtin_amdgcn_s_setprio(0);
    __builtin_amdgcn_sched_barrier(0);
    if (t + 1 < NT) { asm volatile("s_waitcnt vmcnt(0)" ::: "memory"); }
    __builtin_amdgcn_s_barrier();
  }
#undef STAGE

  if constexpr (QKV) {
    const bool isv = (nbase >= 2048);
#pragma unroll
    for (int i = 0; i < 4; ++i) {
#pragma unroll
      for (int j = 0; j < 4; ++j) {
        const long m0 = mbase + wm + i * 16 + l16 * 4;
        const int n = (int)nbase + wn + j * 16 + l15;
        const float bv = bias[n];
        if (!isv) {
          u16* qkp = (u16*)Cp;
          const float sc = (n < 1024) ? SC : 1.0f;
#pragma unroll
          for (int r = 0; r < 4; ++r)
            qkp[(m0 + r) * 2048 + n] = f2bf((acc[i][j][r] + bv) * sc);
        } else {
          const int vc = n - 2048, hh = vc >> 6, dd = vc & 63;
          const int bb = (int)(m0 >> 11), t0 = (int)(m0 & 2047);
          u16x4 pk;
#pragma unroll
          for (int r = 0; r < 4; ++r) pk[r] = f2bf(acc[i][j][r] + bv);
          *(u16x4*)(vt + ((size_t)(bb * 16 + hh) * 64 + dd) * 2048 + t0) = pk;
        }
      }
    }
  } else {
#pragma unroll
    for (int i = 0; i < 4; ++i) {
#pragma unroll
      for (int j = 0; j < 4; ++j) {
        const long row0 = mbase + wm + i * 16 + l16 * 4;
        const long col = nbase + wn + j * 16 + l15;
        const float bv = bias[col];
#pragma unroll
        for (int r = 0; r < 4; ++r)
          ((float*)Cp)[(row0 + r) * (long)N + col] = acc[i][j][r] + bv;
      }
    }
  }
}

// ---------------- flash v6: r8 geometry + DMA staging + shift-free + tile-skip ----------------
// grid 512 (8 pairs x 64 bh); block = 256 thr = 4 waves x 32 q (QBLK=128).
// Paired q-tiles {p,15-p}: 34 KV-iters/block, 2 blocks/CU -> 8 waves/CU.
// Swapped QK^T at 32x32; P redistribution = 16 cvt_pk + 8 permlane32_swap (no LDS).
// K,V staged via global_load_lds DMA (pre-swizzled source, linear dest), dbuf,
// one vmcnt(0)+barrier per iter. Softmax p = exp2(s) (shift cancels exactly).
// Waves 0,1 skip their fully-masked last tile (barriers still executed).
__global__ __launch_bounds__(256, 2) void flash_kernel(
    const u16* __restrict__ qk, const u16* __restrict__ vt, u16* __restrict__ attn_out) {
  __shared__ u16 Ks[2][64 * 64];  // [buf][key][64 d], slot^=(row&7) swizzle
  __shared__ u16 Vs[2][64 * 64];  // [buf][d][64 key]
  const int tid = threadIdx.x;
  const int lane = tid & 63, w = tid >> 6;
  const int l31 = lane & 31, hi = lane >> 5;
  const int xorv = (l31 & 7) << 4;

  const u32 i = blockIdx.y * 8 + blockIdx.x;
  const int jj = i >> 3;
  const int bh = (i & 7) | ((jj & 7) << 3);
  const int pair = (int)(i >> 6);
  const int b = bh >> 4, h = bh & 15;
  const u16* qbase = qk + (size_t)b * 2048 * 2048 + h * 64;
  const u16* kbase = qbase + 1024;
  const u16* vbase = vt + (size_t)bh * 64 * 2048;
  u16* obase = attn_out + (size_t)b * 2048 * 1024 + h * 64;

  // DMA staging: 256 threads cover 32 rows x 8 slots per chunk; 2 chunks per 64-row tile.
  const int sr = tid >> 3;                 // 0..31
  const int ss = (tid & 7) ^ (sr & 7);     // pre-swizzled 16B slot
  const u16* gk = kbase + (size_t)sr * 2048 + ss * 8;
  const u16* gv = vbase + (size_t)sr * 2048 + ss * 8;

  int cur = 0;
  for (int half = 0; half < 2; ++half) {
    const int qt = half ? (15 - pair) : pair;
    const int nt = 2 * qt + 2;
    const int qr0 = qt * 128 + w * 32;
    const int q = qr0 + l31;
    const int ktmax = 2 * qt + (w >> 1);  // waves 0,1: skip last (fully-masked) tile

    // Q B-frags: col=q, k(d) = ds*16 + hi*8 + e
    bf16x8 qf[4];
#pragma unroll
    for (int ds = 0; ds < 4; ++ds)
      qf[ds] = *(const bf16x8*)(qbase + (size_t)q * 2048 + ds * 16 + hi * 8);

    f32x16 oacc[2] = {};
    float lsum = 0.f;

    // prologue: DMA K,V tile 0 into buf[cur]
    gld16(gk, &Ks[cur][tid * 8]);
    gld16(gk + (size_t)32 * 2048, &Ks[cur][tid * 8 + 2048]);
    gld16(gv, &Vs[cur][tid * 8]);
    gld16(gv + (size_t)32 * 2048, &Vs[cur][tid * 8 + 2048]);
    asm volatile("s_waitcnt vmcnt(0)" ::: "memory");
    __builtin_amdgcn_s_barrier();

    for (int kt = 0; kt < nt; ++kt) {
      const int kb = kt * 64;
      if (kt + 1 < nt) {  // DMA next tile into other buffer; lands under compute
        gld16(gk + (size_t)(kb + 64) * 2048, &Ks[cur ^ 1][tid * 8]);
        gld16(gk + (size_t)(kb + 96) * 2048, &Ks[cur ^ 1][tid * 8 + 2048]);
        gld16(gv + (size_t)(kb + 64), &Vs[cur ^ 1][tid * 8]);
        gld16(gv + (size_t)32 * 2048 + (kb + 64), &Vs[cur ^ 1][tid * 8 + 2048]);
      }

      if (kt <= ktmax) {
        // S^T = K Q^T (two 32-key halves), A = K rows from LDS
        f32x16 s0 = {}, s1 = {};
        __builtin_amdgcn_s_setprio(1);
#pragma unroll
        for (int ds = 0; ds < 4; ++ds) {
          const int col = (ds * 32 + hi * 16) ^ xorv;
          bf16x8 k0 = *(const bf16x8*)((const char*)&Ks[cur][0] + l31 * 128 + col);
          bf16x8 k1 = *(const bf16x8*)((const char*)&Ks[cur][0] + (32 + l31) * 128 + col);
          s0 = mfma32(k0, qf[ds], s0);
          s1 = mfma32(k1, qf[ds], s1);
        }
        __builtin_amdgcn_s_setprio(0);

        if (kb + 63 > qr0) {  // causal mask (tiles crossing this wave's diagonal)
#pragma unroll
          for (int r = 0; r < 16; ++r) {
            const int crow = (r & 3) + 8 * (r >> 2) + 4 * hi;
            if (kb + crow > q) s0[r] = -1e30f;
            if (kb + 32 + crow > q) s1[r] = -1e30f;
          }
        }

        // p = exp2(s); per-lane lsum; pack to PV B-frags in-register
        float p0[16], p1[16];
        float ps = 0.f;
#pragma unroll
        for (int r = 0; r < 16; ++r) {
          p0[r] = exp2f(s0[r]);
          p1[r] = exp2f(s1[r]);
          ps += p0[r] + p1[r];
        }
        lsum += ps;

        bf16x8 pf[4];
#pragma unroll
        for (int kh = 0; kh < 2; ++kh) {
#pragma unroll
          for (int c = 0; c < 2; ++c) {
            const float* pp = kh ? p1 : p0;
            const int bs = c * 8;
            u32 L0 = cvtpk(pp[bs + 0], pp[bs + 1]);
            u32 L1 = cvtpk(pp[bs + 2], pp[bs + 3]);
            u32 L2 = cvtpk(pp[bs + 4], pp[bs + 5]);
            u32 L3 = cvtpk(pp[bs + 6], pp[bs + 7]);
            asm("v_permlane32_swap_b32 %0, %1" : "+v"(L0), "+v"(L2));
            asm("v_permlane32_swap_b32 %0, %1" : "+v"(L1), "+v"(L3));
            u32x4 pk = {L0, L1, L2, L3};
            pf[kh * 2 + c] = __builtin_bit_cast(bf16x8, pk);
          }
        }

        // O^T += V^T P : A = V^T rows (d) from LDS, B = pf
        __builtin_amdgcn_s_setprio(1);
#pragma unroll
        for (int dh = 0; dh < 2; ++dh)
#pragma unroll
          for (int ks = 0; ks < 4; ++ks) {
            const int col = (ks * 32 + hi * 16) ^ xorv;
            bf16x8 vf = *(const bf16x8*)((const char*)&Vs[cur][0] + (dh * 32 + l31) * 128 + col);
            oacc[dh] = mfma32(vf, pf[ks], oacc[dh]);
          }
        __builtin_amdgcn_s_setprio(0);
      }

      asm volatile("s_waitcnt vmcnt(0)" ::: "memory");  // next-tile DMAs resident
      __builtin_amdgcn_s_barrier();                     // all waves done with buf[cur]
      cur ^= 1;
    }

    // epilogue: full row-sum (partner holds other 32 keys), lane-local normalize
    lsum += __shfl_xor(lsum, 32);
    const float inv = 1.0f / lsum;
    u16* orow = obase + (size_t)q * 1024;
#pragma unroll
    for (int dh = 0; dh < 2; ++dh) {
#pragma unroll
      for (int jq = 0; jq < 4; ++jq) {
        u32x2 pk;
        pk[0] = cvtpk(oacc[dh][jq * 4 + 0] * inv, oacc[dh][jq * 4 + 1] * inv);
        pk[1] = cvtpk(oacc[dh][jq * 4 + 2] * inv, oacc[dh][jq * 4 + 3] * inv);
        *(u32x2*)(orow + dh * 32 + 8 * jq + 4 * hi) = pk;
      }
    }
  }
}

extern "C" void kernel_launch(void* const* d_in, const int* in_sizes, int n_in,
                              void* d_out, int out_size, void* d_ws, size_t ws_size,
                              hipStream_t stream) {
  (void)in_sizes; (void)n_in; (void)out_size; (void)ws_size;
  const float* x      = (const float*)d_in[0];  // [4,2048,1024]
  const float* w_attn = (const float*)d_in[1];  // [1024,3072]
  const float* b_attn = (const float*)d_in[2];  // [3072]
  const float* w_proj = (const float*)d_in[3];  // [1024,1024]
  const float* b_proj = (const float*)d_in[4];  // [1024]
  float* out = (float*)d_out;                   // [4,2048,1024] f32

  char* ws = (char*)d_ws;
  u16* qkbuf = (u16*)(ws);                   // 33,554,432 B
  u16* vtbuf = (u16*)(ws + 33554432);        // 16,777,216 B
  u16* xbf   = (u16*)(ws + 50331648);        // 16,777,216 B (reused as attn after QKV)
  u16* attnb = (u16*)(ws + 50331648);
  u16* wtA   = (u16*)(ws + 67108864);        //  6,291,456 B
  u16* wtP   = (u16*)(ws + 73400320);        //  2,097,152 B

  conv_kernel<<<4096, 256, 0, stream>>>(x, xbf);
  transpose_conv_kernel<<<dim3(3072 / 32, 1024 / 32), dim3(32, 8), 0, stream>>>(w_attn, wtA, 1024, 3072);
  transpose_conv_kernel<<<dim3(1024 / 32, 1024 / 32), dim3(32, 8), 0, stream>>>(w_proj, wtP, 1024, 1024);

  // QKV GEMM: xbf[8192,1024] @ w_attn^T -> qk (Q pre-scaled) + vT
  gemm_kernel<true><<<dim3(3072 / 128, 8192 / 128), 256, 0, stream>>>(
      xbf, wtA, b_attn, qkbuf, vtbuf, 8192, 3072, 1024);

  // flash attention (512 paired blocks, 2/CU, 8 waves/CU)
  flash_kernel<<<dim3(8, 64), 256, 0, stream>>>(qkbuf, vtbuf, attnb);

  // output projection
  gemm_kernel<false><<<dim3(1024 / 128, 8192 / 128), 256, 0, stream>>>(
      attnb, wtP, b_proj, out, nullptr, 8192, 1024, 1024);
}